// Round 13
// baseline (916.598 us; speedup 1.0000x reference)
//
#include <hip/hip_runtime.h>
#include <math.h>

typedef unsigned short u16;
typedef short bf16x8 __attribute__((ext_vector_type(8)));
typedef float f32x4 __attribute__((ext_vector_type(4)));
typedef u16 u16x4 __attribute__((ext_vector_type(4)));
typedef u16 u16x8 __attribute__((ext_vector_type(8)));

#define NB 2
#define NS 2048
#define ND 512
#define NH 8
#define NHD 64
#define NL 8
#define NFF 2048
#define NM (NB*NS)      // 4096 rows
#define NE 1248
#define NEP 1280        // padded K for input proj
#define NXC 576         // padded K for cat proj (544 -> 576)
#define CHK 64
#define NCH (NS/CHK)    // 32 chunks
#define QKVW 1536       // fused qkv row width

__device__ inline float b2f(u16 u){ union{ unsigned int i; float f;} x; x.i = ((unsigned int)u)<<16; return x.f; }
__device__ inline u16 f2b(float f){ union{ float f; unsigned int i;} x; x.f=f; unsigned int r = x.i + 0x7fffu + ((x.i>>16)&1u); return (u16)(r>>16); }

#define GLL(src, dst) __builtin_amdgcn_global_load_lds( \
    (__attribute__((address_space(1))) void*)(void*)(src), \
    (__attribute__((address_space(3))) void*)(dst), 16, 0, 0)

// ---------------------------------------------------------------- embedding gather+concat (scaled) -> bf16, K padded to 1280
__global__ void k_embed(const int* __restrict__ inp,
    const float* __restrict__ e0, const float* __restrict__ e1, const float* __restrict__ e2,
    const float* __restrict__ e3, const float* __restrict__ e4, const float* __restrict__ e5,
    const float* __restrict__ e6, u16* __restrict__ xe)
{
  int row = blockIdx.x;
  int i0 = inp[row*7+0], i1 = inp[row*7+1], i2 = inp[row*7+2], i3 = inp[row*7+3],
      i4 = inp[row*7+4], i5 = inp[row*7+5], i6 = inp[row*7+6];
  size_t base = (size_t)row*NEP;
  for (int c = threadIdx.x; c < NEP; c += 256){
    float val = 0.f;
    if      (c < 128)  val = e0[i0*128 + c]        * 11.3137084990f;
    else if (c < 384)  val = e1[i1*256 + (c-128)]  * 16.0f;
    else if (c < 448)  val = e2[i2*64  + (c-384)]  * 8.0f;
    else if (c < 480)  val = e3[i3*32  + (c-448)]  * 5.6568542495f;
    else if (c < 992)  val = e4[i4*512 + (c-480)]  * 22.6274169980f;
    else if (c < 1120) val = e5[i5*128 + (c-992)]  * 11.3137084990f;
    else if (c < NE)   val = e6[i6*128 + (c-1120)] * 11.3137084990f;
    xe[base + c] = f2b(val);
  }
}

// ---------------------------------------------------------------- fp32 [K][N] -> bf16 [N][Kpad] transpose, 64k x 128n tile (16KB LDS)
__device__ inline void trans_tile64(const float* __restrict__ W, u16* __restrict__ WT,
                                    int K, int N, int Kpad, int bx, int by){
  __shared__ u16 t[128*64];
  int tid = threadIdx.x;
  int k0 = by*64, n0 = bx*128;
  int c = tid & 31, kg = tid >> 5;    // c: n-group of 4, kg: k-granule 0..7
  u16 r0[8], r1[8], r2[8], r3[8];
  #pragma unroll
  for (int j=0;j<8;j++){
    int k = k0 + kg*8 + j;
    float4 v = {0.f,0.f,0.f,0.f};
    if (k < K) v = *(const float4*)(W + (size_t)k*N + n0 + c*4);
    r0[j] = f2b(v.x); r1[j] = f2b(v.y); r2[j] = f2b(v.z); r3[j] = f2b(v.w);
  }
  #pragma unroll
  for (int i=0;i<4;i++){
    int n = c*4 + i;
    int g = kg ^ (c & 7);
    const u16* rp = (i==0)?r0:(i==1)?r1:(i==2)?r2:r3;
    *(u16x8*)&t[n*64 + g*8] = *(const u16x8*)rp;
  }
  __syncthreads();
  int kg2 = tid & 7, nsub = tid >> 3;   // 32 n-rows per pass
  #pragma unroll
  for (int p=0;p<4;p++){
    int nl = p*32 + nsub;
    int k = k0 + kg2*8;
    if (k < Kpad)
      *(u16x8*)(WT + (size_t)(n0+nl)*Kpad + k) = *(const u16x8*)&t[nl*64 + ((kg2 ^ ((nl>>2)&7))<<3)];
  }
}

// ---------------------------------------------------------------- ALL weight prep in one launch (3956 blocks)
__global__ void k_prep(const float* __restrict__ Wq, const float* __restrict__ Wk,
                       const float* __restrict__ Wv, const float* __restrict__ Wo,
                       const float* __restrict__ in_W, const float* __restrict__ catW,
                       const float* __restrict__ W1, const float* __restrict__ W2,
                       u16* __restrict__ qkvoT, u16* __restrict__ inWT, u16* __restrict__ catWT,
                       u16* __restrict__ w1T, u16* __restrict__ w2T,
                       float* __restrict__ rc, float* __restrict__ rs,
                       const float* p0,const float* p1,const float* p2,const float* p3,
                       const float* p4,const float* p5,const float* p6,
                       const float* q0,const float* q1,const float* q2,const float* q3,
                       const float* q4,const float* q5,const float* q6,
                       u16* __restrict__ pwcT, float* __restrict__ pbc,
                       u16* __restrict__ ptT, float* __restrict__ pbt,
                       const float* __restrict__ bq, const float* __restrict__ bk,
                       const float* __restrict__ bv, float* __restrict__ bqkv,
                       const float* __restrict__ in_b, float* __restrict__ bias_in)
{
  int bid = blockIdx.x;
  if (bid < 1024){
    int z = bid >> 5, r = bid & 31;     // 32 matrices x (4n x 8k)
    int l = z >> 2, s2 = z & 3;
    const float* W = (s2==0?Wq:s2==1?Wk:s2==2?Wv:Wo) + (size_t)l*ND*ND;
    trans_tile64(W, qkvoT + (size_t)z*ND*ND, ND, ND, ND, r & 3, r >> 2);
  } else if (bid < 1104){
    int r = bid - 1024;                 // 80 blocks (4n x 20k)
    trans_tile64(in_W, inWT, NE, ND, NEP, r & 3, r >> 2);
  } else if (bid < 1140){
    int r = bid - 1104;                 // 36 blocks (4n x 9k)
    trans_tile64(catW, catWT, 544, ND, NXC, r & 3, r >> 2);
  } else if (bid < 2164){
    int r = bid - 1140;                 // 1024: 8 layers x (16n x 8k)
    int l = r >> 7; int rr = r & 127;
    trans_tile64(W1 + (size_t)l*ND*NFF, w1T + (size_t)l*ND*NFF, ND, NFF, ND, rr & 15, rr >> 4);
  } else if (bid < 3188){
    int r = bid - 2164;                 // 1024: 8 layers x (4n x 32k)
    int l = r >> 7; int rr = r & 127;
    trans_tile64(W2 + (size_t)l*NFF*ND, w2T + (size_t)l*ND*NFF, NFF, ND, NFF, rr & 3, rr >> 2);
  } else {
    int idx = (bid - 3188)*256 + threadIdx.x;
    if (idx < NS*32){
      int s = idx >> 5, j = idx & 31;
      double inv = exp(-(double)(2*j) * log(10000.0) / (double)NHD);
      double ang = (double)s * inv;
      rc[idx] = (float)cos(ang);
      rs[idx] = (float)sin(ang);
    }
    const int off[8] = {0,56,191,209,213,300,318,343};
    {
      int col = idx >> 9, k = idx & 511;
      if (col < 384){
        u16 v = 0;
        if (col < 343){
          int f = 0;
          while (col >= off[f+1]) f++;
          int cc = col - off[f];
          int V = off[f+1]-off[f];
          const float* P = (f==0)?p0:(f==1)?p1:(f==2)?p2:(f==3)?p3:(f==4)?p4:(f==5)?p5:p6;
          v = f2b(P[(size_t)k*V + cc] * sqrtf((float)V));
        }
        pwcT[(size_t)col*512 + k] = v;
      }
      if (idx < 64*512){
        int n = idx >> 9;
        ptT[idx] = (n < 4) ? f2b(p3[(size_t)k*4 + n]*2.0f) : (u16)0;
      }
    }
    if (idx < 343){
      int c2 = idx, f = 0;
      while (c2 >= off[f+1]) f++;
      int cc = c2 - off[f]; int V = off[f+1]-off[f];
      const float* Q = (f==0)?q0:(f==1)?q1:(f==2)?q2:(f==3)?q3:(f==4)?q4:(f==5)?q5:q6;
      pbc[idx] = Q[cc]*sqrtf((float)V);
    }
    if (idx < 4) pbt[idx] = q3[idx]*2.0f;
    if (idx < NL*QKVW){
      int l = idx / QKVW, c = idx % QKVW;
      float v = (c < 512) ? bq[l*512 + c] : (c < 1024) ? bk[l*512 + c - 512] : bv[l*512 + c - 1024];
      bqkv[idx] = v;
    }
    if (idx < ND){
      double div = exp(-(double)(idx & ~1) * log(10000.0) / (double)ND);
      double ang = (double)NS * div;
      float pev = (idx & 1) ? (float)cos(ang) : (float)sin(ang);
      bias_in[idx] = in_b[idx] + pev;
    }
  }
}

// ---------------------------------------------------------------- bf16 MFMA GEMM
// TM x (NT*32) tile, BK=64, single-buffer LDS, 2-barrier loop,
// pre-swizzled conflict-free staging, XCD-aware block swizzle.
// ACT: 0=none, 1=gelu, 2=rope+phi epilogue via LDS round-trip (QKV, 64x64).
// blockIdx.z = split-K piece (A,BT advanced by koff; z>0 writes Cf2, no bias/resid).
// resid: optional fp32 residual added in epilogue (kz==0 only).
template<int ACT, int NT, int TM>
__global__ __launch_bounds__(256) void k_gemm(
    const u16* __restrict__ A, const u16* __restrict__ BT,
    const float* __restrict__ bias, float* __restrict__ Cf, u16* __restrict__ Cb,
    int N, int klen, int lda, int ldb, int ldc,
    int koff, float* __restrict__ Cf2,
    const float* __restrict__ rc, const float* __restrict__ rs,
    const float* __restrict__ resid)
{
  constexpr int MREP = TM/32;
  __shared__ u16 SH[TM*64 + NT*32*64];
  u16* As = SH;
  u16* Bs = SH + TM*64;
  int tid = threadIdx.x;
  int w = tid >> 6, lane = tid & 63;

  int kz = blockIdx.z;
  A  += (size_t)kz*koff;
  BT += (size_t)kz*koff;
  if (kz){ Cf = Cf2; bias = nullptr; resid = nullptr; }

  // XCD-aware chunked remap
  int nwg = gridDim.x*gridDim.y;
  int d = blockIdx.y*gridDim.x + blockIdx.x;
  int wl = ((nwg & 7) == 0) ? ((d & 7)*(nwg >> 3) + (d >> 3)) : d;
  int bx = wl % gridDim.x, by = wl / gridDim.x;
  int m0 = by*TM, n0 = bx*(NT*32);

  f32x4 acc[MREP][NT];
  #pragma unroll
  for (int m=0;m<MREP;m++)
    #pragma unroll
    for (int n=0;n<NT;n++) acc[m][n] = (f32x4){0.f,0.f,0.f,0.f};

  int lg = lane>>3;                 // row within 8-row staging group
  int cg = (lane&7) ^ lg;           // pre-swizzled source granule
  const u16* ag = A  + (size_t)(m0 + w*(TM/4) + lg)*lda + cg*8;
  const u16* bg = BT + (size_t)(n0 + w*(NT*8) + lg)*ldb + cg*8;
  int wr = (w>>1)*(TM/2), wc = (w&1)*(NT*16);
  int lr = lane & 15;
  int rx = lr & 7;                  // read-side row xor
  int cb_ = lane >> 4;              // fragment k-granule base
  int g = lane >> 4;

  int nk = klen >> 6;
  for (int t = 0; t < nk; ++t){
    int k0 = t << 6;
    #pragma unroll
    for (int i=0;i<TM/32;i++)
      GLL(ag + (size_t)(i*8)*lda + k0, &As[(w*(TM/4) + i*8)*64]);
    #pragma unroll
    for (int j=0;j<NT;j++)
      GLL(bg + (size_t)(j*8)*ldb + k0, &Bs[(w*(NT*8) + j*8)*64]);
    __syncthreads();
    #pragma unroll
    for (int kk=0;kk<2;kk++){
      int gA = ((kk*4 + cb_) ^ rx) * 8;
      bf16x8 af[MREP], bfr[NT];
      #pragma unroll
      for (int m=0;m<MREP;m++) af[m]  = *(const bf16x8*)&As[(wr + m*16 + lr)*64 + gA];
      #pragma unroll
      for (int n=0;n<NT;n++)   bfr[n] = *(const bf16x8*)&Bs[(wc + n*16 + lr)*64 + gA];
      #pragma unroll
      for (int m=0;m<MREP;m++)
        #pragma unroll
        for (int n=0;n<NT;n++)
          acc[m][n] = __builtin_amdgcn_mfma_f32_16x16x32_bf16(af[m], bfr[n], acc[m][n], 0,0,0);
    }
    __syncthreads();
  }

  if (ACT == 2){
    // rope+phi epilogue via LDS round-trip (TM=64, NT=2: 64x64 tile = 16KB fp32)
    float* Cs = (float*)SH;
    #pragma unroll
    for (int n=0;n<NT;n++){
      int col = wc + n*16 + lr;
      float bv = bias ? bias[n0 + col] : 0.f;
      #pragma unroll
      for (int m=0;m<MREP;m++)
        #pragma unroll
        for (int r=0;r<4;r++)
          Cs[(wr + m*16 + g*4 + r)*64 + col] = acc[m][n][r] + bv;
    }
    __syncthreads();
    if (n0 < 1024){
      // q or k section: rope + phi on pairs (j, j+32)
      #pragma unroll
      for (int i=0;i<8;i++){
        int p = tid + i*256;           // 2048 pairs = 64 rows x 32
        int row = p >> 5, j = p & 31;
        float a1 = Cs[row*64 + j], a2 = Cs[row*64 + j + 32];
        int s = (m0 + row) & (NS-1);
        float c = rc[s*32+j], sn = rs[s*32+j];
        float r1 = a1*c - a2*sn, r2 = a2*c + a1*sn;
        Cb[(size_t)(m0+row)*ldc + n0 + j]      = f2b((r1 > 0.f) ? r1+1.f : expf(r1));
        Cb[(size_t)(m0+row)*ldc + n0 + j + 32] = f2b((r2 > 0.f) ? r2+1.f : expf(r2));
      }
    } else {
      // v section: plain bias write
      #pragma unroll
      for (int i=0;i<16;i++){
        int p = tid + i*256;           // 4096 = 64 x 64
        int row = p >> 6, c2 = p & 63;
        Cb[(size_t)(m0+row)*ldc + n0 + c2] = f2b(Cs[row*64 + c2]);
      }
    }
    return;
  }

  #pragma unroll
  for (int n=0;n<NT;n++){
    int col = n0 + wc + n*16 + lr;
    if (col < N){
      float bv = bias ? bias[col] : 0.f;
      #pragma unroll
      for (int m=0;m<MREP;m++){
        #pragma unroll
        for (int r=0;r<4;r++){
          int row = m0 + wr + m*16 + g*4 + r;
          float v = acc[m][n][r] + bv;
          if (ACT==1) v = 0.5f*v*(1.f+erff(v*0.70710678118654752f));
          if (resid) v += resid[(size_t)row*ldc + col];
          if (Cf) Cf[(size_t)row*ldc + col] = v;
          if (Cb) Cb[(size_t)row*ldc + col] = f2b(v);
        }
      }
    }
  }
}

// ---------------------------------------------------------------- att1: per-chunk [V^T;1]·K -> prefb tile (bf16, xor-swizzled)
__global__ __launch_bounds__(256) void k_att1(const u16* __restrict__ qkv, u16* __restrict__ prefb){
  int c = blockIdx.x, h = blockIdx.y, b = blockIdx.z;
  __shared__ u16 Kt[64*64];   // [m][t] xor-swizzled
  __shared__ u16 Vt[80*64];   // [d_ext][t] xor-swizzled; row64=ones, 65-79=0
  int tid = threadIdx.x;
  {
    int t = tid & 63, dseg = (tid>>6)*16;
    const u16* kg = qkv + ((size_t)(b*NS + c*CHK + t))*QKVW + 512 + h*NHD + dseg;
    u16x8 k0 = *(const u16x8*)kg;
    u16x8 k1 = *(const u16x8*)(kg+8);
    u16x8 v0 = *(const u16x8*)(kg+512);
    u16x8 v1 = *(const u16x8*)(kg+520);
    #pragma unroll
    for (int e=0;e<8;e++){
      int d0 = dseg+e, d1 = dseg+8+e;
      Kt[(d0*64+t) ^ ((d0&7)<<3)] = k0[e];
      Kt[(d1*64+t) ^ ((d1&7)<<3)] = k1[e];
      Vt[(d0*64+t) ^ ((d0&7)<<3)] = v0[e];
      Vt[(d1*64+t) ^ ((d1&7)<<3)] = v1[e];
    }
    if (tid < 64) Vt[4096 + tid] = 0x3F80;   // ones row (row 64, swz=0)
    for (int e = tid; e < 15*64; e += 256){
      int r = 65 + (e>>6), tt = e&63;
      Vt[(r*64+tt) ^ ((r&7)<<3)] = 0;
    }
  }
  __syncthreads();
  int lane = tid & 63, w = tid >> 6;
  int lr = lane & 15, lk = (lane>>4)*8;
  f32x4 acc[5];
  #pragma unroll
  for (int i=0;i<5;i++) acc[i] = (f32x4){0.f,0.f,0.f,0.f};
  #pragma unroll
  for (int kk=0;kk<2;kk++){
    int mcol = w*16 + lr;
    bf16x8 bfrag = *(const bf16x8*)&Kt[(mcol*64 + kk*32 + lk) ^ ((mcol&7)<<3)];
    #pragma unroll
    for (int fr=0; fr<5; fr++){
      int arow = fr*16 + lr;
      bf16x8 afrag = *(const bf16x8*)&Vt[(arow*64 + kk*32 + lk) ^ ((arow&7)<<3)];
      acc[fr] = __builtin_amdgcn_mfma_f32_16x16x32_bf16(afrag, bfrag, acc[fr], 0,0,0);
    }
  }
  size_t pbase = (((size_t)(b*NH + h))*NCH + c)*5120;
  int g = lane>>4;
  #pragma unroll
  for (int fr=0; fr<5; fr++)
    #pragma unroll
    for (int r=0;r<4;r++){
      int row = fr*16 + g*4 + r;
      int idx = row*64 + w*16 + lr;
      prefb[pbase + (idx ^ ((row&7)<<3))] = f2b(acc[fr][r]);
    }
}

// ---------------------------------------------------------------- att2: in-place exclusive prefix over 32 chunks (bf16, fp32 run)
__global__ __launch_bounds__(256) void k_att2(u16* __restrict__ prefb){
  int bh = blockIdx.y;
  int e = blockIdx.x*256 + threadIdx.x;   // 0..5119 (physical/swizzled index)
  size_t base = (size_t)bh*NCH*5120 + e;
  float v[NCH];
  #pragma unroll
  for (int c=0;c<NCH;c++) v[c] = b2f(prefb[base + (size_t)c*5120]);
  float run = 0.f;
  #pragma unroll
  for (int c=0;c<NCH;c++){ prefb[base + (size_t)c*5120] = f2b(run); run += v[c]; }
}

// ---------------------------------------------------------------- att3: MFMA in-chunk attention
// S^T = K·Q^T (masked), O = S·[V|1] + Q·[pkv^T|pks]; col 64 = denominator
// Q/K/Ps staged via global_load_lds (pre-swizzled sources); Sm aliases Ks.
__global__ __launch_bounds__(256) void k_att3(const u16* __restrict__ qkv,
    const u16* __restrict__ prefb, u16* __restrict__ outa)
{
  int c = blockIdx.x, h = blockIdx.y, b = blockIdx.z;
  __shared__ u16 Qs[4096], Ks[4096];             // [row][64] xor-swz; Sm aliases Ks
  __shared__ u16 Vt[5120], Ps[5120];             // [80][64] xor-swz
  __shared__ float dens[64];
  u16* Sm = Ks;
  int tid = threadIdx.x;
  int lane = tid & 63, w = tid >> 6;
  {
    // Q and K via global_load_lds, pre-swizzled per-lane source
    int r8 = lane >> 3;
    int gsw = (lane & 7) ^ r8;
    const u16* qbase = qkv + ((size_t)(b*NS + c*CHK))*QKVW + h*NHD + gsw*8;
    #pragma unroll
    for (int half = 0; half < 2; half++){
      int rbase = w*16 + half*8;
      const u16* src = qbase + (size_t)(rbase + r8)*QKVW;
      GLL(src,       &Qs[rbase*64]);
      GLL(src + 512, &Ks[rbase*64]);
    }
    // Ps via global_load_lds from pre-swizzled bf16 prefix (linear copy)
    const u16* pb = prefb + (((size_t)(b*NH + h))*NCH + c)*5120 + lane*8;
    for (int ch = w; ch < 10; ch += 4)
      GLL(pb + ch*512, &Ps[ch*512]);
  }
  {
    // V manual transposed staging (genuinely strided)
    int t = tid&63, dseg = (tid>>6)*16;
    const u16* vg = qkv + ((size_t)(b*NS + c*CHK + t))*QKVW + 1024 + h*NHD + dseg;
    u16x8 v0 = *(const u16x8*)vg;
    u16x8 v1 = *(const u16x8*)(vg+8);
    #pragma unroll
    for (int e=0;e<8;e++){
      int d0=dseg+e, d1=dseg+8+e;
      Vt[(d0*64+t)^((d0&7)<<3)] = v0[e];
      Vt[(d1*64+t)^((d1&7)<<3)] = v1[e];
    }
    if (tid<64) Vt[4096+tid] = 0x3F80;
    for (int e=tid; e<15*64; e+=256){
      int r = 65+(e>>6), tt = e&63;
      Vt[(r*64+tt)^((r&7)<<3)] = 0;
    }
  }
  __syncthreads();
  int lr = lane&15, lk = (lane>>4)*8, g = lane>>4;
  // phase A: S^T[t][i] for this wave's i-strip
  f32x4 sacc[4];
  #pragma unroll
  for (int i=0;i<4;i++) sacc[i] = (f32x4){0.f,0.f,0.f,0.f};
  int iq = w*16 + lr;
  #pragma unroll
  for (int kk=0;kk<2;kk++){
    bf16x8 bq = *(const bf16x8*)&Qs[(iq*64 + kk*32 + lk) ^ ((iq&7)<<3)];
    #pragma unroll
    for (int ft=0; ft<4; ft++){
      int tr = ft*16 + lr;
      bf16x8 ak = *(const bf16x8*)&Ks[(tr*64 + kk*32 + lk) ^ ((tr&7)<<3)];
      sacc[ft] = __builtin_amdgcn_mfma_f32_16x16x32_bf16(ak, bq, sacc[ft], 0,0,0);
    }
  }
  __syncthreads();   // all waves done READING Ks before Sm overwrites it
  // masked write S[i][t] (b64 per fragment) into Sm (= Ks region)
  #pragma unroll
  for (int ft=0; ft<4; ft++){
    int t0 = ft*16 + g*4;
    u16x4 pk;
    #pragma unroll
    for (int r=0;r<4;r++) pk[r] = f2b((t0+r <= iq) ? sacc[ft][r] : 0.f);
    *(u16x4*)&Sm[(iq*64 + t0) ^ ((iq&7)<<3)] = pk;
  }
  __syncthreads();
  // phase B: O[i][col] = S·[V|1] + Q·[pkv^T|pks]
  f32x4 acc[5];
  #pragma unroll
  for (int i=0;i<5;i++) acc[i] = (f32x4){0.f,0.f,0.f,0.f};
  #pragma unroll
  for (int kk=0;kk<2;kk++){
    int sw = (iq&7)<<3;
    bf16x8 as = *(const bf16x8*)&Sm[(iq*64 + kk*32 + lk) ^ sw];
    bf16x8 aq = *(const bf16x8*)&Qs[(iq*64 + kk*32 + lk) ^ sw];
    #pragma unroll
    for (int c5=0;c5<5;c5++){
      int col = c5*16 + lr, sw2 = (col&7)<<3;
      bf16x8 bv = *(const bf16x8*)&Vt[(col*64 + kk*32 + lk) ^ sw2];
      bf16x8 bp = *(const bf16x8*)&Ps[(col*64 + kk*32 + lk) ^ sw2];
      acc[c5] = __builtin_amdgcn_mfma_f32_16x16x32_bf16(as, bv, acc[c5], 0,0,0);
      acc[c5] = __builtin_amdgcn_mfma_f32_16x16x32_bf16(aq, bp, acc[c5], 0,0,0);
    }
  }
  if (lr == 0){
    #pragma unroll
    for (int r=0;r<4;r++) dens[w*16 + g*4 + r] = acc[4][r];
  }
  __syncthreads();
  #pragma unroll
  for (int c5=0;c5<4;c5++){
    #pragma unroll
    for (int r=0;r<4;r++){
      int i = w*16 + g*4 + r;
      float z = 1.f/(dens[i] + 1e-6f);
      outa[((size_t)(b*NS + c*CHK + i))*ND + h*NHD + c5*16 + lr] = f2b(acc[c5][r]*z);
    }
  }
}

// ---------------------------------------------------------------- layernorm with up to two residual partials
// optional xcb epilogue: write [ln_row | emb_type(target)*sqrt(32) | 0pad] bf16 (576-wide)
__global__ __launch_bounds__(256) void k_ln(const float* __restrict__ xin, const float* __restrict__ res,
    const float* __restrict__ res2, float* __restrict__ outx, u16* __restrict__ outb,
    const float* __restrict__ g, const float* __restrict__ bvec,
    const int* __restrict__ tgt, const float* __restrict__ embt, u16* __restrict__ xcb)
{
  int row = blockIdx.x, tid = threadIdx.x;
  size_t base = (size_t)row*ND;
  float v0 = xin[base+tid], v1 = xin[base+tid+256];
  if (res){ v0 += res[base+tid]; v1 += res[base+tid+256]; }
  if (res2){ v0 += res2[base+tid]; v1 += res2[base+tid+256]; }
  float s = v0+v1, ss2 = v0*v0 + v1*v1;
  #pragma unroll
  for (int o = 32; o >= 1; o >>= 1){
    s   += __shfl_down(s, o, 64);
    ss2 += __shfl_down(ss2, o, 64);
  }
  __shared__ float red[8];
  int wv = tid >> 6, ln = tid & 63;
  if (ln == 0){ red[wv] = s; red[4+wv] = ss2; }
  __syncthreads();
  float stot  = red[0]+red[1]+red[2]+red[3];
  float sstot = red[4]+red[5]+red[6]+red[7];
  float mean = stot * (1.0f/ND);
  float var  = sstot * (1.0f/ND) - mean*mean;
  float inv = 1.0f / sqrtf(var + 1e-5f);
  float o0 = (v0-mean)*inv*g[tid]     + bvec[tid];
  float o1 = (v1-mean)*inv*g[tid+256] + bvec[tid+256];
  outx[base+tid] = o0; outx[base+tid+256] = o1;
  if (outb){ outb[base+tid] = f2b(o0); outb[base+tid+256] = f2b(o1); }
  if (xcb){
    size_t xbse = (size_t)row*NXC;
    xcb[xbse+tid] = f2b(o0);
    xcb[xbse+tid+256] = f2b(o1);
    if (tid < 32){
      int id = tgt[row*7+3];
      xcb[xbse+512+tid] = f2b(embt[id*32+tid]*5.6568542495f);
      xcb[xbse+544+tid] = 0;
    }
  }
}

// ================================================================ host
extern "C" void kernel_launch(void* const* d_in, const int* in_sizes, int n_in,
                              void* d_out, int out_size, void* d_ws, size_t ws_size,
                              hipStream_t stream)
{
  const int* inputs = (const int*)d_in[0];
  const int* target = (const int*)d_in[1];
  const float* emb[7];
  for (int i=0;i<7;i++) emb[i] = (const float*)d_in[2+i];
  const float* in_W  = (const float*)d_in[9];
  const float* in_b  = (const float*)d_in[10];
  const float* Wq = (const float*)d_in[11];
  const float* Wk = (const float*)d_in[12];
  const float* Wv = (const float*)d_in[13];
  const float* Wo = (const float*)d_in[14];
  const float* W1 = (const float*)d_in[15];
  const float* W2 = (const float*)d_in[16];
  const float* bq = (const float*)d_in[17];
  const float* bk = (const float*)d_in[18];
  const float* bv = (const float*)d_in[19];
  const float* bo = (const float*)d_in[20];
  const float* b1 = (const float*)d_in[21];
  const float* b2 = (const float*)d_in[22];
  const float* ln1_b = (const float*)d_in[23];
  const float* ln2_b = (const float*)d_in[24];
  const float* norm_b = (const float*)d_in[25];
  const float* catb   = (const float*)d_in[26];
  const float* ln1_g = (const float*)d_in[27];
  const float* ln2_g = (const float*)d_in[28];
  const float* norm_g = (const float*)d_in[29];
  const float* pW[7]; const float* pb[7];
  for (int i=0;i<7;i++){ pW[i]=(const float*)d_in[30+2*i]; pb[i]=(const float*)d_in[31+2*i]; }
  const float* catW = (const float*)d_in[44];
  float* outp = (float*)d_out;

  char* base = (char*)d_ws;
  size_t off = 0;
  auto alloc = [&](size_t bytes)->void*{ void* p = base + off; off += bytes; off = (off + 255) & ~(size_t)255; return p; };

  float* x    = (float*)alloc((size_t)NM*ND*4);
  u16*   xb   = (u16*)  alloc((size_t)NM*ND*2);
  u16*   qkvb = (u16*)  alloc((size_t)NM*QKVW*2);
  float* tb   = (float*)alloc((size_t)NM*ND*4);
  float* tb2  = (float*)alloc((size_t)NM*ND*4);
  u16*   ab   = (u16*)  alloc((size_t)NM*ND*2);
  u16*   hb   = (u16*)  alloc((size_t)NM*NFF*2);   // aliases: xe[NM,1280], xc[NM,576]+oc[NM,512]
  float* rc   = (float*)alloc((size_t)NS*32*4);
  float* rs   = (float*)alloc((size_t)NS*32*4);
  u16*  prefb = (u16*)  alloc((size_t)NB*NH*NCH*5120*2);
  u16*  qkvoT = (u16*)  alloc((size_t)NL*4*ND*ND*2);
  u16*  w1T   = (u16*)  alloc((size_t)NL*NFF*ND*2);   // all layers
  u16*  w2T   = (u16*)  alloc((size_t)NL*ND*NFF*2);   // all layers
  u16*  inWT  = (u16*)  alloc((size_t)ND*NEP*2);
  u16*  catWT = (u16*)  alloc((size_t)ND*NXC*2);
  u16*  pwcT  = (u16*)  alloc((size_t)384*512*2);
  float* pbc  = (float*)alloc(344*4);
  u16*  ptT   = (u16*)  alloc((size_t)64*512*2);
  float* pbt  = (float*)alloc(4*4);
  float* bqkv = (float*)alloc((size_t)NL*QKVW*4);
  float* bias_in = (float*)alloc(ND*4);
  u16*  xeb = hb;
  u16*  xcb = hb;
  u16*  ocb = hb + (size_t)NM*NXC;

  // weight + misc prep: ONE launch
  k_prep<<<3956, 256, 0, stream>>>(Wq, Wk, Wv, Wo, in_W, catW, W1, W2,
      qkvoT, inWT, catWT, w1T, w2T, rc, rs,
      pW[0],pW[1],pW[2],pW[3],pW[4],pW[5],pW[6],
      pb[0],pb[1],pb[2],pb[3],pb[4],pb[5],pb[6],
      pwcT, pbc, ptT, pbt, bq, bk, bv, bqkv, in_b, bias_in);

  // embedding + input projection (bias = in_b + pe, dual write x/xb)
  k_embed<<<NM, 256, 0, stream>>>(inputs, emb[0],emb[1],emb[2],emb[3],emb[4],emb[5],emb[6], xeb);
  k_gemm<0,2,64><<<dim3(8,64,1), 256, 0, stream>>>(xeb, inWT, bias_in, x, xb,
      ND, NEP, NEP, NEP, ND, 0, nullptr, nullptr, nullptr, nullptr);

  dim3 agrid(NCH, NH, NB);
  for (int l = 0; l < NL; l++){
    const u16* woT = qkvoT + (size_t)(l*4+3)*ND*ND;
    // fused QKV GEMM + rope + phi (64x64 tile: block covers one head section)
    k_gemm<2,2,64><<<dim3(24,64,1), 256, 0, stream>>>(xb, qkvoT + (size_t)l*4*ND*ND,
        bqkv + l*QKVW, nullptr, qkvb, QKVW, ND, ND, ND, QKVW, 0, nullptr, rc, rs, nullptr);
    k_att1<<<agrid, 256, 0, stream>>>(qkvb, prefb);
    k_att2<<<dim3(20,16), 256, 0, stream>>>(prefb);
    k_att3<<<agrid, 256, 0, stream>>>(qkvb, prefb, ab);
    // Wo (unsplit, K=512) with fused residual: tb = x + ab@Wo + bo
    k_gemm<0,2,64><<<dim3(8,64,1), 256, 0, stream>>>(ab, woT, bo + l*ND, tb, nullptr,
        ND, ND, ND, ND, ND, 0, nullptr, nullptr, nullptr, x);
    k_ln<<<NM, 256, 0, stream>>>(tb, nullptr, nullptr, x, xb, ln1_g + l*ND, ln1_b + l*ND,
                                 nullptr, nullptr, nullptr);
    k_gemm<1,2,64><<<dim3(32,64,1), 256, 0, stream>>>(xb, w1T + (size_t)l*NFF*ND,
        b1 + l*NFF, nullptr, hb, NFF, ND, ND, ND, NFF, 0, nullptr, nullptr, nullptr, nullptr);
    // W2 split-K=2, z=0 adds residual x
    k_gemm<0,2,64><<<dim3(8,64,2), 256, 0, stream>>>(hb, w2T + (size_t)l*ND*NFF,
        b2 + l*ND, tb, nullptr, ND, 1024, NFF, NFF, ND, 1024, tb2, nullptr, nullptr, x);
    k_ln<<<NM, 256, 0, stream>>>(tb, tb2, nullptr, x, xb, ln2_g + l*ND, ln2_b + l*ND,
                                 nullptr, nullptr, nullptr);
  }

  // final LN (writes x, xb, and xcb = [ln | emb_type | pad] directly)
  k_ln<<<NM, 256, 0, stream>>>(x, nullptr, nullptr, x, xb, norm_g, norm_b,
                               target, emb[3], xcb);

  // heads
  k_gemm<0,2,64><<<dim3(8,64,1), 256, 0, stream>>>(xcb, catWT, catb, nullptr, ocb,
      ND, NXC, NXC, NXC, ND, 0, nullptr, nullptr, nullptr, nullptr);
  k_gemm<0,2,64><<<dim3(6,64,1), 256, 0, stream>>>(ocb, pwcT, pbc, outp, nullptr,
      343, ND, ND, ND, 343, 0, nullptr, nullptr, nullptr, nullptr);
  k_gemm<0,2,64><<<dim3(1,64,1), 256, 0, stream>>>(xb, ptT, pbt, outp + 209, nullptr,
      4, ND, ND, ND, 343, 0, nullptr, nullptr, nullptr, nullptr);
}

// Round 15
// 801.266 us; speedup vs baseline: 1.1439x; 1.1439x over previous
//
#include <hip/hip_runtime.h>
#include <math.h>

typedef unsigned short u16;
typedef short bf16x8 __attribute__((ext_vector_type(8)));
typedef float f32x4 __attribute__((ext_vector_type(4)));
typedef u16 u16x4 __attribute__((ext_vector_type(4)));
typedef u16 u16x8 __attribute__((ext_vector_type(8)));

#define NB 2
#define NS 2048
#define ND 512
#define NH 8
#define NHD 64
#define NL 8
#define NFF 2048
#define NM (NB*NS)      // 4096 rows
#define NE 1248
#define NEP 1280        // padded K for input proj
#define NXC 576         // padded K for cat proj (544 -> 576)
#define CHK 64
#define NCH (NS/CHK)    // 32 chunks
#define QKVW 1536       // fused qkv row width

__device__ inline float b2f(u16 u){ union{ unsigned int i; float f;} x; x.i = ((unsigned int)u)<<16; return x.f; }
__device__ inline u16 f2b(float f){ union{ float f; unsigned int i;} x; x.f=f; unsigned int r = x.i + 0x7fffu + ((x.i>>16)&1u); return (u16)(r>>16); }

#define GLL(src, dst) __builtin_amdgcn_global_load_lds( \
    (__attribute__((address_space(1))) void*)(void*)(src), \
    (__attribute__((address_space(3))) void*)(dst), 16, 0, 0)

// ---------------------------------------------------------------- embedding gather+concat (scaled) -> bf16, K padded to 1280
__global__ void k_embed(const int* __restrict__ inp,
    const float* __restrict__ e0, const float* __restrict__ e1, const float* __restrict__ e2,
    const float* __restrict__ e3, const float* __restrict__ e4, const float* __restrict__ e5,
    const float* __restrict__ e6, u16* __restrict__ xe)
{
  int row = blockIdx.x;
  int i0 = inp[row*7+0], i1 = inp[row*7+1], i2 = inp[row*7+2], i3 = inp[row*7+3],
      i4 = inp[row*7+4], i5 = inp[row*7+5], i6 = inp[row*7+6];
  size_t base = (size_t)row*NEP;
  for (int c = threadIdx.x; c < NEP; c += 256){
    float val = 0.f;
    if      (c < 128)  val = e0[i0*128 + c]        * 11.3137084990f;
    else if (c < 384)  val = e1[i1*256 + (c-128)]  * 16.0f;
    else if (c < 448)  val = e2[i2*64  + (c-384)]  * 8.0f;
    else if (c < 480)  val = e3[i3*32  + (c-448)]  * 5.6568542495f;
    else if (c < 992)  val = e4[i4*512 + (c-480)]  * 22.6274169980f;
    else if (c < 1120) val = e5[i5*128 + (c-992)]  * 11.3137084990f;
    else if (c < NE)   val = e6[i6*128 + (c-1120)] * 11.3137084990f;
    xe[base + c] = f2b(val);
  }
}

// ---------------------------------------------------------------- fp32 [K][N] -> bf16 [N][Kpad] transpose, 64k x 128n tile (16KB LDS)
__device__ inline void trans_tile64(const float* __restrict__ W, u16* __restrict__ WT,
                                    int K, int N, int Kpad, int bx, int by){
  __shared__ u16 t[128*64];
  int tid = threadIdx.x;
  int k0 = by*64, n0 = bx*128;
  int c = tid & 31, kg = tid >> 5;    // c: n-group of 4, kg: k-granule 0..7
  u16 r0[8], r1[8], r2[8], r3[8];
  #pragma unroll
  for (int j=0;j<8;j++){
    int k = k0 + kg*8 + j;
    float4 v = {0.f,0.f,0.f,0.f};
    if (k < K) v = *(const float4*)(W + (size_t)k*N + n0 + c*4);
    r0[j] = f2b(v.x); r1[j] = f2b(v.y); r2[j] = f2b(v.z); r3[j] = f2b(v.w);
  }
  #pragma unroll
  for (int i=0;i<4;i++){
    int n = c*4 + i;
    int g = kg ^ (c & 7);
    const u16* rp = (i==0)?r0:(i==1)?r1:(i==2)?r2:r3;
    *(u16x8*)&t[n*64 + g*8] = *(const u16x8*)rp;
  }
  __syncthreads();
  int kg2 = tid & 7, nsub = tid >> 3;   // 32 n-rows per pass
  #pragma unroll
  for (int p=0;p<4;p++){
    int nl = p*32 + nsub;
    int k = k0 + kg2*8;
    if (k < Kpad)
      *(u16x8*)(WT + (size_t)(n0+nl)*Kpad + k) = *(const u16x8*)&t[nl*64 + ((kg2 ^ ((nl>>2)&7))<<3)];
  }
}

// ---------------------------------------------------------------- ALL weight prep in one launch (3956 blocks)
__global__ void k_prep(const float* __restrict__ Wq, const float* __restrict__ Wk,
                       const float* __restrict__ Wv, const float* __restrict__ Wo,
                       const float* __restrict__ in_W, const float* __restrict__ catW,
                       const float* __restrict__ W1, const float* __restrict__ W2,
                       u16* __restrict__ qkvoT, u16* __restrict__ inWT, u16* __restrict__ catWT,
                       u16* __restrict__ w1T, u16* __restrict__ w2T,
                       float* __restrict__ rc, float* __restrict__ rs,
                       const float* p0,const float* p1,const float* p2,const float* p3,
                       const float* p4,const float* p5,const float* p6,
                       const float* q0,const float* q1,const float* q2,const float* q3,
                       const float* q4,const float* q5,const float* q6,
                       u16* __restrict__ pwcT, float* __restrict__ pbc,
                       u16* __restrict__ ptT, float* __restrict__ pbt,
                       const float* __restrict__ bq, const float* __restrict__ bk,
                       const float* __restrict__ bv, float* __restrict__ bqkv,
                       const float* __restrict__ in_b, float* __restrict__ bias_in)
{
  int bid = blockIdx.x;
  if (bid < 1024){
    int z = bid >> 5, r = bid & 31;     // 32 matrices x (4n x 8k)
    int l = z >> 2, s2 = z & 3;
    const float* W = (s2==0?Wq:s2==1?Wk:s2==2?Wv:Wo) + (size_t)l*ND*ND;
    trans_tile64(W, qkvoT + (size_t)z*ND*ND, ND, ND, ND, r & 3, r >> 2);
  } else if (bid < 1104){
    int r = bid - 1024;                 // 80 blocks (4n x 20k)
    trans_tile64(in_W, inWT, NE, ND, NEP, r & 3, r >> 2);
  } else if (bid < 1140){
    int r = bid - 1104;                 // 36 blocks (4n x 9k)
    trans_tile64(catW, catWT, 544, ND, NXC, r & 3, r >> 2);
  } else if (bid < 2164){
    int r = bid - 1140;                 // 1024: 8 layers x (16n x 8k)
    int l = r >> 7; int rr = r & 127;
    trans_tile64(W1 + (size_t)l*ND*NFF, w1T + (size_t)l*ND*NFF, ND, NFF, ND, rr & 15, rr >> 4);
  } else if (bid < 3188){
    int r = bid - 2164;                 // 1024: 8 layers x (4n x 32k)
    int l = r >> 7; int rr = r & 127;
    trans_tile64(W2 + (size_t)l*NFF*ND, w2T + (size_t)l*ND*NFF, NFF, ND, NFF, rr & 3, rr >> 2);
  } else {
    int idx = (bid - 3188)*256 + threadIdx.x;
    if (idx < NS*32){
      int s = idx >> 5, j = idx & 31;
      double inv = exp(-(double)(2*j) * log(10000.0) / (double)NHD);
      double ang = (double)s * inv;
      rc[idx] = (float)cos(ang);
      rs[idx] = (float)sin(ang);
    }
    const int off[8] = {0,56,191,209,213,300,318,343};
    {
      int col = idx >> 9, k = idx & 511;
      if (col < 384){
        u16 v = 0;
        if (col < 343){
          int f = 0;
          while (col >= off[f+1]) f++;
          int cc = col - off[f];
          int V = off[f+1]-off[f];
          const float* P = (f==0)?p0:(f==1)?p1:(f==2)?p2:(f==3)?p3:(f==4)?p4:(f==5)?p5:p6;
          v = f2b(P[(size_t)k*V + cc] * sqrtf((float)V));
        }
        pwcT[(size_t)col*512 + k] = v;
      }
      if (idx < 64*512){
        int n = idx >> 9;
        ptT[idx] = (n < 4) ? f2b(p3[(size_t)k*4 + n]*2.0f) : (u16)0;
      }
    }
    if (idx < 343){
      int c2 = idx, f = 0;
      while (c2 >= off[f+1]) f++;
      int cc = c2 - off[f]; int V = off[f+1]-off[f];
      const float* Q = (f==0)?q0:(f==1)?q1:(f==2)?q2:(f==3)?q3:(f==4)?q4:(f==5)?q5:q6;
      pbc[idx] = Q[cc]*sqrtf((float)V);
    }
    if (idx < 4) pbt[idx] = q3[idx]*2.0f;
    if (idx < NL*QKVW){
      int l = idx / QKVW, c = idx % QKVW;
      float v = (c < 512) ? bq[l*512 + c] : (c < 1024) ? bk[l*512 + c - 512] : bv[l*512 + c - 1024];
      bqkv[idx] = v;
    }
    if (idx < ND){
      double div = exp(-(double)(idx & ~1) * log(10000.0) / (double)ND);
      double ang = (double)NS * div;
      float pev = (idx & 1) ? (float)cos(ang) : (float)sin(ang);
      bias_in[idx] = in_b[idx] + pev;
    }
  }
}

// ---------------------------------------------------------------- bf16 MFMA GEMM
// TM x (NT*32) tile, BK=64, single-buffer LDS, 2-barrier loop,
// pre-swizzled conflict-free staging, XCD-aware block swizzle.
// ACT: 0=none, 1=gelu, 2=rope+phi epilogue via LDS round-trip (QKV, 64x64).
// blockIdx.z = split-K piece (A,BT advanced by koff; z>0 writes Cf2, no bias).
template<int ACT, int NT, int TM>
__global__ __launch_bounds__(256) void k_gemm(
    const u16* __restrict__ A, const u16* __restrict__ BT,
    const float* __restrict__ bias, float* __restrict__ Cf, u16* __restrict__ Cb,
    int N, int klen, int lda, int ldb, int ldc,
    int koff, float* __restrict__ Cf2,
    const float* __restrict__ rc, const float* __restrict__ rs)
{
  constexpr int MREP = TM/32;
  __shared__ u16 SH[TM*64 + NT*32*64];
  u16* As = SH;
  u16* Bs = SH + TM*64;
  int tid = threadIdx.x;
  int w = tid >> 6, lane = tid & 63;

  int kz = blockIdx.z;
  A  += (size_t)kz*koff;
  BT += (size_t)kz*koff;
  if (kz){ Cf = Cf2; bias = nullptr; }

  // XCD-aware chunked remap
  int nwg = gridDim.x*gridDim.y;
  int d = blockIdx.y*gridDim.x + blockIdx.x;
  int wl = ((nwg & 7) == 0) ? ((d & 7)*(nwg >> 3) + (d >> 3)) : d;
  int bx = wl % gridDim.x, by = wl / gridDim.x;
  int m0 = by*TM, n0 = bx*(NT*32);

  f32x4 acc[MREP][NT];
  #pragma unroll
  for (int m=0;m<MREP;m++)
    #pragma unroll
    for (int n=0;n<NT;n++) acc[m][n] = (f32x4){0.f,0.f,0.f,0.f};

  int lg = lane>>3;                 // row within 8-row staging group
  int cg = (lane&7) ^ lg;           // pre-swizzled source granule
  const u16* ag = A  + (size_t)(m0 + w*(TM/4) + lg)*lda + cg*8;
  const u16* bg = BT + (size_t)(n0 + w*(NT*8) + lg)*ldb + cg*8;
  int wr = (w>>1)*(TM/2), wc = (w&1)*(NT*16);
  int lr = lane & 15;
  int rx = lr & 7;                  // read-side row xor
  int cb_ = lane >> 4;              // fragment k-granule base
  int g = lane >> 4;

  int nk = klen >> 6;
  for (int t = 0; t < nk; ++t){
    int k0 = t << 6;
    #pragma unroll
    for (int i=0;i<TM/32;i++)
      GLL(ag + (size_t)(i*8)*lda + k0, &As[(w*(TM/4) + i*8)*64]);
    #pragma unroll
    for (int j=0;j<NT;j++)
      GLL(bg + (size_t)(j*8)*ldb + k0, &Bs[(w*(NT*8) + j*8)*64]);
    __syncthreads();
    #pragma unroll
    for (int kk=0;kk<2;kk++){
      int gA = ((kk*4 + cb_) ^ rx) * 8;
      bf16x8 af[MREP], bfr[NT];
      #pragma unroll
      for (int m=0;m<MREP;m++) af[m]  = *(const bf16x8*)&As[(wr + m*16 + lr)*64 + gA];
      #pragma unroll
      for (int n=0;n<NT;n++)   bfr[n] = *(const bf16x8*)&Bs[(wc + n*16 + lr)*64 + gA];
      #pragma unroll
      for (int m=0;m<MREP;m++)
        #pragma unroll
        for (int n=0;n<NT;n++)
          acc[m][n] = __builtin_amdgcn_mfma_f32_16x16x32_bf16(af[m], bfr[n], acc[m][n], 0,0,0);
    }
    __syncthreads();
  }

  if (ACT == 2){
    // rope+phi epilogue via LDS round-trip (TM=64, NT=2: 64x64 tile = 16KB fp32)
    float* Cs = (float*)SH;
    #pragma unroll
    for (int n=0;n<NT;n++){
      int col = wc + n*16 + lr;
      float bv = bias ? bias[n0 + col] : 0.f;
      #pragma unroll
      for (int m=0;m<MREP;m++)
        #pragma unroll
        for (int r=0;r<4;r++)
          Cs[(wr + m*16 + g*4 + r)*64 + col] = acc[m][n][r] + bv;
    }
    __syncthreads();
    if (n0 < 1024){
      // q or k section: rope + phi on pairs (j, j+32)
      #pragma unroll
      for (int i=0;i<8;i++){
        int p = tid + i*256;           // 2048 pairs = 64 rows x 32
        int row = p >> 5, j = p & 31;
        float a1 = Cs[row*64 + j], a2 = Cs[row*64 + j + 32];
        int s = (m0 + row) & (NS-1);
        float c = rc[s*32+j], sn = rs[s*32+j];
        float r1 = a1*c - a2*sn, r2 = a2*c + a1*sn;
        Cb[(size_t)(m0+row)*ldc + n0 + j]      = f2b((r1 > 0.f) ? r1+1.f : expf(r1));
        Cb[(size_t)(m0+row)*ldc + n0 + j + 32] = f2b((r2 > 0.f) ? r2+1.f : expf(r2));
      }
    } else {
      // v section: plain bias write
      #pragma unroll
      for (int i=0;i<16;i++){
        int p = tid + i*256;           // 4096 = 64 x 64
        int row = p >> 6, c2 = p & 63;
        Cb[(size_t)(m0+row)*ldc + n0 + c2] = f2b(Cs[row*64 + c2]);
      }
    }
    return;
  }

  #pragma unroll
  for (int n=0;n<NT;n++){
    int col = n0 + wc + n*16 + lr;
    if (col < N){
      float bv = bias ? bias[col] : 0.f;
      #pragma unroll
      for (int m=0;m<MREP;m++){
        #pragma unroll
        for (int r=0;r<4;r++){
          int row = m0 + wr + m*16 + g*4 + r;
          float v = acc[m][n][r] + bv;
          if (ACT==1) v = 0.5f*v*(1.f+erff(v*0.70710678118654752f));
          if (Cf) Cf[(size_t)row*ldc + col] = v;
          if (Cb) Cb[(size_t)row*ldc + col] = f2b(v);
        }
      }
    }
  }
}

// ---------------------------------------------------------------- merged head GEMMs
// bx<6: ocb@pwcT -> outp cols 0..342 EXCEPT 209..212 (owned by type head);
// bx==6: xb@ptT -> outp cols 209..212.
__global__ __launch_bounds__(256) void k_heads(
    const u16* __restrict__ A1, const u16* __restrict__ BT1, const float* __restrict__ b1v,
    const u16* __restrict__ A2, const u16* __restrict__ BT2, const float* __restrict__ b2v,
    float* __restrict__ outp)
{
  __shared__ u16 SH[64*64 + 64*64];
  u16* As = SH;
  u16* Bs = SH + 64*64;
  int tid = threadIdx.x;
  int w = tid >> 6, lane = tid & 63;

  int nwg = gridDim.x*gridDim.y;
  int d = blockIdx.y*gridDim.x + blockIdx.x;
  int wl = ((nwg & 7) == 0) ? ((d & 7)*(nwg >> 3) + (d >> 3)) : d;
  int bx = wl % gridDim.x, by = wl / gridDim.x;
  int m0 = by*64;

  const u16* A; const u16* BT; const float* bias; float* Cf; int N, n0; bool main343;
  if (bx < 6){ A = A1; BT = BT1; bias = b1v; Cf = outp;       N = 343; n0 = bx*64; main343 = true; }
  else       { A = A2; BT = BT2; bias = b2v; Cf = outp + 209; N = 4;   n0 = 0;     main343 = false; }

  f32x4 acc[2][2];
  #pragma unroll
  for (int m=0;m<2;m++)
    #pragma unroll
    for (int n=0;n<2;n++) acc[m][n] = (f32x4){0.f,0.f,0.f,0.f};

  int lg = lane>>3;
  int cg = (lane&7) ^ lg;
  const u16* ag = A  + (size_t)(m0 + w*16 + lg)*ND + cg*8;
  const u16* bg = BT + (size_t)(n0 + w*16 + lg)*ND + cg*8;
  int wr = (w>>1)*32, wc = (w&1)*32;
  int lr = lane & 15;
  int rx = lr & 7;
  int cb_ = lane >> 4;
  int g = lane >> 4;

  for (int t = 0; t < 8; ++t){
    int k0 = t << 6;
    #pragma unroll
    for (int i=0;i<2;i++)
      GLL(ag + (size_t)(i*8)*ND + k0, &As[(w*16 + i*8)*64]);
    #pragma unroll
    for (int j=0;j<2;j++)
      GLL(bg + (size_t)(j*8)*ND + k0, &Bs[(w*16 + j*8)*64]);
    __syncthreads();
    #pragma unroll
    for (int kk=0;kk<2;kk++){
      int gA = ((kk*4 + cb_) ^ rx) * 8;
      bf16x8 af[2], bfr[2];
      #pragma unroll
      for (int m=0;m<2;m++) af[m]  = *(const bf16x8*)&As[(wr + m*16 + lr)*64 + gA];
      #pragma unroll
      for (int n=0;n<2;n++) bfr[n] = *(const bf16x8*)&Bs[(wc + n*16 + lr)*64 + gA];
      #pragma unroll
      for (int m=0;m<2;m++)
        #pragma unroll
        for (int n=0;n<2;n++)
          acc[m][n] = __builtin_amdgcn_mfma_f32_16x16x32_bf16(af[m], bfr[n], acc[m][n], 0,0,0);
    }
    __syncthreads();
  }
  #pragma unroll
  for (int n=0;n<2;n++){
    int col = n0 + wc + n*16 + lr;
    bool skip = main343 && (col >= 209 && col < 213);   // type head owns these
    if (col < N && !skip){
      float bv = bias[col];
      #pragma unroll
      for (int m=0;m<2;m++){
        #pragma unroll
        for (int r=0;r<4;r++){
          int row = m0 + wr + m*16 + g*4 + r;
          Cf[(size_t)row*343 + col] = acc[m][n][r] + bv;
        }
      }
    }
  }
}

// ---------------------------------------------------------------- att1: per-chunk [V^T;1]·K -> prefb tile (bf16, xor-swizzled)
__global__ __launch_bounds__(256) void k_att1(const u16* __restrict__ qkv, u16* __restrict__ prefb){
  int c = blockIdx.x, h = blockIdx.y, b = blockIdx.z;
  __shared__ u16 Kt[64*64];   // [m][t] xor-swizzled
  __shared__ u16 Vt[80*64];   // [d_ext][t] xor-swizzled; row64=ones, 65-79=0
  int tid = threadIdx.x;
  {
    int t = tid & 63, dseg = (tid>>6)*16;
    const u16* kg = qkv + ((size_t)(b*NS + c*CHK + t))*QKVW + 512 + h*NHD + dseg;
    u16x8 k0 = *(const u16x8*)kg;
    u16x8 k1 = *(const u16x8*)(kg+8);
    u16x8 v0 = *(const u16x8*)(kg+512);
    u16x8 v1 = *(const u16x8*)(kg+520);
    #pragma unroll
    for (int e=0;e<8;e++){
      int d0 = dseg+e, d1 = dseg+8+e;
      Kt[(d0*64+t) ^ ((d0&7)<<3)] = k0[e];
      Kt[(d1*64+t) ^ ((d1&7)<<3)] = k1[e];
      Vt[(d0*64+t) ^ ((d0&7)<<3)] = v0[e];
      Vt[(d1*64+t) ^ ((d1&7)<<3)] = v1[e];
    }
    if (tid < 64) Vt[4096 + tid] = 0x3F80;   // ones row (row 64, swz=0)
    for (int e = tid; e < 15*64; e += 256){
      int r = 65 + (e>>6), tt = e&63;
      Vt[(r*64+tt) ^ ((r&7)<<3)] = 0;
    }
  }
  __syncthreads();
  int lane = tid & 63, w = tid >> 6;
  int lr = lane & 15, lk = (lane>>4)*8;
  f32x4 acc[5];
  #pragma unroll
  for (int i=0;i<5;i++) acc[i] = (f32x4){0.f,0.f,0.f,0.f};
  #pragma unroll
  for (int kk=0;kk<2;kk++){
    int mcol = w*16 + lr;
    bf16x8 bfrag = *(const bf16x8*)&Kt[(mcol*64 + kk*32 + lk) ^ ((mcol&7)<<3)];
    #pragma unroll
    for (int fr=0; fr<5; fr++){
      int arow = fr*16 + lr;
      bf16x8 afrag = *(const bf16x8*)&Vt[(arow*64 + kk*32 + lk) ^ ((arow&7)<<3)];
      acc[fr] = __builtin_amdgcn_mfma_f32_16x16x32_bf16(afrag, bfrag, acc[fr], 0,0,0);
    }
  }
  size_t pbase = (((size_t)(b*NH + h))*NCH + c)*5120;
  int g = lane>>4;
  #pragma unroll
  for (int fr=0; fr<5; fr++)
    #pragma unroll
    for (int r=0;r<4;r++){
      int row = fr*16 + g*4 + r;
      int idx = row*64 + w*16 + lr;
      prefb[pbase + (idx ^ ((row&7)<<3))] = f2b(acc[fr][r]);
    }
}

// ---------------------------------------------------------------- att2: in-place exclusive prefix over 32 chunks (bf16, fp32 run)
__global__ __launch_bounds__(256) void k_att2(u16* __restrict__ prefb){
  int bh = blockIdx.y;
  int e = blockIdx.x*256 + threadIdx.x;   // 0..5119 (physical/swizzled index)
  size_t base = (size_t)bh*NCH*5120 + e;
  float v[NCH];
  #pragma unroll
  for (int c=0;c<NCH;c++) v[c] = b2f(prefb[base + (size_t)c*5120]);
  float run = 0.f;
  #pragma unroll
  for (int c=0;c<NCH;c++){ prefb[base + (size_t)c*5120] = f2b(run); run += v[c]; }
}

// ---------------------------------------------------------------- att3: MFMA in-chunk attention
// S^T = K·Q^T (masked), O = S·[V|1] + Q·[pkv^T|pks]; col 64 = denominator
// Q/K/Ps staged via global_load_lds (pre-swizzled sources); Sm aliases Ks.
__global__ __launch_bounds__(256) void k_att3(const u16* __restrict__ qkv,
    const u16* __restrict__ prefb, u16* __restrict__ outa)
{
  int c = blockIdx.x, h = blockIdx.y, b = blockIdx.z;
  __shared__ u16 Qs[4096], Ks[4096];             // [row][64] xor-swz; Sm aliases Ks
  __shared__ u16 Vt[5120], Ps[5120];             // [80][64] xor-swz
  __shared__ float dens[64];
  u16* Sm = Ks;
  int tid = threadIdx.x;
  int lane = tid & 63, w = tid >> 6;
  {
    // Q and K via global_load_lds, pre-swizzled per-lane source
    int r8 = lane >> 3;
    int gsw = (lane & 7) ^ r8;
    const u16* qbase = qkv + ((size_t)(b*NS + c*CHK))*QKVW + h*NHD + gsw*8;
    #pragma unroll
    for (int half = 0; half < 2; half++){
      int rbase = w*16 + half*8;
      const u16* src = qbase + (size_t)(rbase + r8)*QKVW;
      GLL(src,       &Qs[rbase*64]);
      GLL(src + 512, &Ks[rbase*64]);
    }
    // Ps via global_load_lds from pre-swizzled bf16 prefix (linear copy)
    const u16* pb = prefb + (((size_t)(b*NH + h))*NCH + c)*5120 + lane*8;
    for (int ch = w; ch < 10; ch += 4)
      GLL(pb + ch*512, &Ps[ch*512]);
  }
  {
    // V manual transposed staging (genuinely strided)
    int t = tid&63, dseg = (tid>>6)*16;
    const u16* vg = qkv + ((size_t)(b*NS + c*CHK + t))*QKVW + 1024 + h*NHD + dseg;
    u16x8 v0 = *(const u16x8*)vg;
    u16x8 v1 = *(const u16x8*)(vg+8);
    #pragma unroll
    for (int e=0;e<8;e++){
      int d0=dseg+e, d1=dseg+8+e;
      Vt[(d0*64+t)^((d0&7)<<3)] = v0[e];
      Vt[(d1*64+t)^((d1&7)<<3)] = v1[e];
    }
    if (tid<64) Vt[4096+tid] = 0x3F80;
    for (int e=tid; e<15*64; e+=256){
      int r = 65+(e>>6), tt = e&63;
      Vt[(r*64+tt)^((r&7)<<3)] = 0;
    }
  }
  __syncthreads();
  int lr = lane&15, lk = (lane>>4)*8, g = lane>>4;
  // phase A: S^T[t][i] for this wave's i-strip
  f32x4 sacc[4];
  #pragma unroll
  for (int i=0;i<4;i++) sacc[i] = (f32x4){0.f,0.f,0.f,0.f};
  int iq = w*16 + lr;
  #pragma unroll
  for (int kk=0;kk<2;kk++){
    bf16x8 bq = *(const bf16x8*)&Qs[(iq*64 + kk*32 + lk) ^ ((iq&7)<<3)];
    #pragma unroll
    for (int ft=0; ft<4; ft++){
      int tr = ft*16 + lr;
      bf16x8 ak = *(const bf16x8*)&Ks[(tr*64 + kk*32 + lk) ^ ((tr&7)<<3)];
      sacc[ft] = __builtin_amdgcn_mfma_f32_16x16x32_bf16(ak, bq, sacc[ft], 0,0,0);
    }
  }
  __syncthreads();   // all waves done READING Ks before Sm overwrites it
  // masked write S[i][t] (b64 per fragment) into Sm (= Ks region)
  #pragma unroll
  for (int ft=0; ft<4; ft++){
    int t0 = ft*16 + g*4;
    u16x4 pk;
    #pragma unroll
    for (int r=0;r<4;r++) pk[r] = f2b((t0+r <= iq) ? sacc[ft][r] : 0.f);
    *(u16x4*)&Sm[(iq*64 + t0) ^ ((iq&7)<<3)] = pk;
  }
  __syncthreads();
  // phase B: O[i][col] = S·[V|1] + Q·[pkv^T|pks]
  f32x4 acc[5];
  #pragma unroll
  for (int i=0;i<5;i++) acc[i] = (f32x4){0.f,0.f,0.f,0.f};
  #pragma unroll
  for (int kk=0;kk<2;kk++){
    int sw = (iq&7)<<3;
    bf16x8 as = *(const bf16x8*)&Sm[(iq*64 + kk*32 + lk) ^ sw];
    bf16x8 aq = *(const bf16x8*)&Qs[(iq*64 + kk*32 + lk) ^ sw];
    #pragma unroll
    for (int c5=0;c5<5;c5++){
      int col = c5*16 + lr, sw2 = (col&7)<<3;
      bf16x8 bv = *(const bf16x8*)&Vt[(col*64 + kk*32 + lk) ^ sw2];
      bf16x8 bp = *(const bf16x8*)&Ps[(col*64 + kk*32 + lk) ^ sw2];
      acc[c5] = __builtin_amdgcn_mfma_f32_16x16x32_bf16(as, bv, acc[c5], 0,0,0);
      acc[c5] = __builtin_amdgcn_mfma_f32_16x16x32_bf16(aq, bp, acc[c5], 0,0,0);
    }
  }
  if (lr == 0){
    #pragma unroll
    for (int r=0;r<4;r++) dens[w*16 + g*4 + r] = acc[4][r];
  }
  __syncthreads();
  #pragma unroll
  for (int c5=0;c5<4;c5++){
    #pragma unroll
    for (int r=0;r<4;r++){
      int i = w*16 + g*4 + r;
      float z = 1.f/(dens[i] + 1e-6f);
      outa[((size_t)(b*NS + c*CHK + i))*ND + h*NHD + c5*16 + lr] = f2b(acc[c5][r]*z);
    }
  }
}

// ---------------------------------------------------------------- layernorm with up to two residual partials
// optional xcb epilogue: write [ln_row | emb_type(target)*sqrt(32) | 0pad] bf16 (576-wide)
__global__ __launch_bounds__(256) void k_ln(const float* __restrict__ xin, const float* __restrict__ res,
    const float* __restrict__ res2, float* __restrict__ outx, u16* __restrict__ outb,
    const float* __restrict__ g, const float* __restrict__ bvec,
    const int* __restrict__ tgt, const float* __restrict__ embt, u16* __restrict__ xcb)
{
  int row = blockIdx.x, tid = threadIdx.x;
  size_t base = (size_t)row*ND;
  float v0 = xin[base+tid], v1 = xin[base+tid+256];
  if (res){ v0 += res[base+tid]; v1 += res[base+tid+256]; }
  if (res2){ v0 += res2[base+tid]; v1 += res2[base+tid+256]; }
  float s = v0+v1, ss2 = v0*v0 + v1*v1;
  #pragma unroll
  for (int o = 32; o >= 1; o >>= 1){
    s   += __shfl_down(s, o, 64);
    ss2 += __shfl_down(ss2, o, 64);
  }
  __shared__ float red[8];
  int wv = tid >> 6, ln = tid & 63;
  if (ln == 0){ red[wv] = s; red[4+wv] = ss2; }
  __syncthreads();
  float stot  = red[0]+red[1]+red[2]+red[3];
  float sstot = red[4]+red[5]+red[6]+red[7];
  float mean = stot * (1.0f/ND);
  float var  = sstot * (1.0f/ND) - mean*mean;
  float inv = 1.0f / sqrtf(var + 1e-5f);
  float o0 = (v0-mean)*inv*g[tid]     + bvec[tid];
  float o1 = (v1-mean)*inv*g[tid+256] + bvec[tid+256];
  outx[base+tid] = o0; outx[base+tid+256] = o1;
  if (outb){ outb[base+tid] = f2b(o0); outb[base+tid+256] = f2b(o1); }
  if (xcb){
    size_t xbse = (size_t)row*NXC;
    xcb[xbse+tid] = f2b(o0);
    xcb[xbse+tid+256] = f2b(o1);
    if (tid < 32){
      int id = tgt[row*7+3];
      xcb[xbse+512+tid] = f2b(embt[id*32+tid]*5.6568542495f);
      xcb[xbse+544+tid] = 0;
    }
  }
}

// ================================================================ host
extern "C" void kernel_launch(void* const* d_in, const int* in_sizes, int n_in,
                              void* d_out, int out_size, void* d_ws, size_t ws_size,
                              hipStream_t stream)
{
  const int* inputs = (const int*)d_in[0];
  const int* target = (const int*)d_in[1];
  const float* emb[7];
  for (int i=0;i<7;i++) emb[i] = (const float*)d_in[2+i];
  const float* in_W  = (const float*)d_in[9];
  const float* in_b  = (const float*)d_in[10];
  const float* Wq = (const float*)d_in[11];
  const float* Wk = (const float*)d_in[12];
  const float* Wv = (const float*)d_in[13];
  const float* Wo = (const float*)d_in[14];
  const float* W1 = (const float*)d_in[15];
  const float* W2 = (const float*)d_in[16];
  const float* bq = (const float*)d_in[17];
  const float* bk = (const float*)d_in[18];
  const float* bv = (const float*)d_in[19];
  const float* bo = (const float*)d_in[20];
  const float* b1 = (const float*)d_in[21];
  const float* b2 = (const float*)d_in[22];
  const float* ln1_b = (const float*)d_in[23];
  const float* ln2_b = (const float*)d_in[24];
  const float* norm_b = (const float*)d_in[25];
  const float* catb   = (const float*)d_in[26];
  const float* ln1_g = (const float*)d_in[27];
  const float* ln2_g = (const float*)d_in[28];
  const float* norm_g = (const float*)d_in[29];
  const float* pW[7]; const float* pb[7];
  for (int i=0;i<7;i++){ pW[i]=(const float*)d_in[30+2*i]; pb[i]=(const float*)d_in[31+2*i]; }
  const float* catW = (const float*)d_in[44];
  float* outp = (float*)d_out;

  char* base = (char*)d_ws;
  size_t off = 0;
  auto alloc = [&](size_t bytes)->void*{ void* p = base + off; off += bytes; off = (off + 255) & ~(size_t)255; return p; };

  float* x    = (float*)alloc((size_t)NM*ND*4);
  u16*   xb   = (u16*)  alloc((size_t)NM*ND*2);
  u16*   qkvb = (u16*)  alloc((size_t)NM*QKVW*2);
  float* tb   = (float*)alloc((size_t)NM*ND*4);
  float* tb2  = (float*)alloc((size_t)NM*ND*4);
  u16*   ab   = (u16*)  alloc((size_t)NM*ND*2);
  u16*   hb   = (u16*)  alloc((size_t)NM*NFF*2);   // aliases: xe[NM,1280], xc[NM,576]+oc[NM,512]
  float* rc   = (float*)alloc((size_t)NS*32*4);
  float* rs   = (float*)alloc((size_t)NS*32*4);
  u16*  prefb = (u16*)  alloc((size_t)NB*NH*NCH*5120*2);
  u16*  qkvoT = (u16*)  alloc((size_t)NL*4*ND*ND*2);
  u16*  w1T   = (u16*)  alloc((size_t)NL*NFF*ND*2);   // all layers
  u16*  w2T   = (u16*)  alloc((size_t)NL*ND*NFF*2);   // all layers
  u16*  inWT  = (u16*)  alloc((size_t)ND*NEP*2);
  u16*  catWT = (u16*)  alloc((size_t)ND*NXC*2);
  u16*  pwcT  = (u16*)  alloc((size_t)384*512*2);
  float* pbc  = (float*)alloc(344*4);
  u16*  ptT   = (u16*)  alloc((size_t)64*512*2);
  float* pbt  = (float*)alloc(4*4);
  float* bqkv = (float*)alloc((size_t)NL*QKVW*4);
  float* bias_in = (float*)alloc(ND*4);
  u16*  xeb = hb;
  u16*  xcb = hb;
  u16*  ocb = hb + (size_t)NM*NXC;

  // weight + misc prep: ONE launch
  k_prep<<<3956, 256, 0, stream>>>(Wq, Wk, Wv, Wo, in_W, catW, W1, W2,
      qkvoT, inWT, catWT, w1T, w2T, rc, rs,
      pW[0],pW[1],pW[2],pW[3],pW[4],pW[5],pW[6],
      pb[0],pb[1],pb[2],pb[3],pb[4],pb[5],pb[6],
      pwcT, pbc, ptT, pbt, bq, bk, bv, bqkv, in_b, bias_in);

  // embedding + input projection (bias = in_b + pe, dual write x/xb)
  k_embed<<<NM, 256, 0, stream>>>(inputs, emb[0],emb[1],emb[2],emb[3],emb[4],emb[5],emb[6], xeb);
  k_gemm<0,2,64><<<dim3(8,64,1), 256, 0, stream>>>(xeb, inWT, bias_in, x, xb,
      ND, NEP, NEP, NEP, ND, 0, nullptr, nullptr, nullptr);

  dim3 agrid(NCH, NH, NB);
  for (int l = 0; l < NL; l++){
    const u16* woT = qkvoT + (size_t)(l*4+3)*ND*ND;
    // fused QKV GEMM + rope + phi (64x64 tile: block covers one head section)
    k_gemm<2,2,64><<<dim3(24,64,1), 256, 0, stream>>>(xb, qkvoT + (size_t)l*4*ND*ND,
        bqkv + l*QKVW, nullptr, qkvb, QKVW, ND, ND, ND, QKVW, 0, nullptr, rc, rs);
    k_att1<<<agrid, 256, 0, stream>>>(qkvb, prefb);
    k_att2<<<dim3(20,16), 256, 0, stream>>>(prefb);
    k_att3<<<agrid, 256, 0, stream>>>(qkvb, prefb, ab);
    // Wo (unsplit, K=512)
    k_gemm<0,2,64><<<dim3(8,64,1), 256, 0, stream>>>(ab, woT, bo + l*ND, tb, nullptr,
        ND, ND, ND, ND, ND, 0, nullptr, nullptr, nullptr);
    k_ln<<<NM, 256, 0, stream>>>(x, tb, nullptr, x, xb, ln1_g + l*ND, ln1_b + l*ND,
                                 nullptr, nullptr, nullptr);
    k_gemm<1,2,64><<<dim3(32,64,1), 256, 0, stream>>>(xb, w1T + (size_t)l*NFF*ND,
        b1 + l*NFF, nullptr, hb, NFF, ND, ND, ND, NFF, 0, nullptr, nullptr, nullptr);
    // W2 split-K=2 in one dispatch
    k_gemm<0,2,64><<<dim3(8,64,2), 256, 0, stream>>>(hb, w2T + (size_t)l*ND*NFF,
        b2 + l*ND, tb, nullptr, ND, 1024, NFF, NFF, ND, 1024, tb2, nullptr, nullptr);
    k_ln<<<NM, 256, 0, stream>>>(x, tb, tb2, x, xb, ln2_g + l*ND, ln2_b + l*ND,
                                 nullptr, nullptr, nullptr);
  }

  // final LN (writes x, xb, and xcb = [ln | emb_type | pad] directly)
  k_ln<<<NM, 256, 0, stream>>>(x, nullptr, nullptr, x, xb, norm_g, norm_b,
                               target, emb[3], xcb);

  // heads: cat proj, then merged 343-col + 4-col projections in one launch
  k_gemm<0,2,64><<<dim3(8,64,1), 256, 0, stream>>>(xcb, catWT, catb, nullptr, ocb,
      ND, NXC, NXC, NXC, ND, 0, nullptr, nullptr, nullptr);
  k_heads<<<dim3(7,64,1), 256, 0, stream>>>(ocb, pwcT, pbc, xb, ptT, pbt, outp);
}